// Round 8
// baseline (357.864 us; speedup 1.0000x reference)
//
#include <hip/hip_runtime.h>
#include <math.h>

// Hash-grid (instant-NGP style) trilinear interpolation, layer 8.
// T = 2^19 entries x F=2 floats; N = 2^21 points x 3 dims.
// Hash: (ix ^ iy*2654435761 ^ iz*805459861) mod 2^19 -- uint32 math is
// bit-exact with the reference's int64 (power-of-two modulus).
//
// Evidence ledger:
//  r1/r3/r6: 62-65us across MLP depth 8->32, requests 16.7M->12.6M,
//    occupancy 69->26% => wall is per-unique-line gather processing
//    (~2.3 cy/lane-gather/CU), L1 hit rate ~1% (4MB table, random).
//  r5: nt gathers broke L2 residency => table must stay normally cached.
//  r7: sc0 (L1 bypass, L2 kept) 25% WORSE => L1 path helps; don't bypass.
// This round: counting-sort points into 26^3 spatial buckets (4^3 cells
// each) so each wave's 64 points share ~100 unique table lines instead
// of ~512 -> TD merge + real L1 hits. Output order restored via stored
// point id (deterministic: each point writes only its own slot).

#define HT_MASK  524287u
#define PRIME_Y  2654435761u
#define PRIME_Z  805459861u
#define N_POINTS 2097152
#define NBD      26                      // ix>>2, ix in [0,100] -> [0,25]
#define NBUCKETS (NBD * NBD * NBD)       // 17576
#define SCAN_THREADS 1024
#define BINS_PER_THREAD 18               // 1024*18 = 18432 >= 17576

typedef float vfloat4 __attribute__((ext_vector_type(4)));
typedef float vfloat2 __attribute__((ext_vector_type(2)));

__device__ __forceinline__ unsigned bucket_of(float px, float py, float pz,
                                              float scale) {
    int ix = (int)floorf(px * scale);
    int iy = (int)floorf(py * scale);
    int iz = (int)floorf(pz * scale);
    return ((unsigned)(ix >> 2) * NBD + (unsigned)(iy >> 2)) * NBD
           + (unsigned)(iz >> 2);
}

// ---- K1: per-bucket histogram ------------------------------------------
__global__ __launch_bounds__(256) void k1_hist(
    const vfloat4* __restrict__ X4, unsigned* __restrict__ hist, float scale)
{
    int t = blockIdx.x * blockDim.x + threadIdx.x;   // 0 .. N/4-1
    vfloat4 q0 = __builtin_nontemporal_load(&X4[3 * t + 0]);
    vfloat4 q1 = __builtin_nontemporal_load(&X4[3 * t + 1]);
    vfloat4 q2 = __builtin_nontemporal_load(&X4[3 * t + 2]);

    float px[4] = {q0.x, q0.w, q1.z, q2.y};
    float py[4] = {q0.y, q1.x, q1.w, q2.z};
    float pz[4] = {q0.z, q1.y, q2.x, q2.w};

    #pragma unroll
    for (int p = 0; p < 4; ++p)
        atomicAdd(&hist[bucket_of(px[p], py[p], pz[p], scale)], 1u);
}

// ---- K2: exclusive scan of 17576 bins (one block) -----------------------
__global__ __launch_bounds__(SCAN_THREADS) void k2_scan(
    const unsigned* __restrict__ hist, unsigned* __restrict__ offs)
{
    __shared__ unsigned part[SCAN_THREADS];
    int tid = threadIdx.x;
    int base = tid * BINS_PER_THREAD;

    unsigned loc[BINS_PER_THREAD];
    unsigned s = 0;
    #pragma unroll
    for (int k = 0; k < BINS_PER_THREAD; ++k) {
        unsigned v = (base + k < NBUCKETS) ? hist[base + k] : 0u;
        loc[k] = s;
        s += v;
    }
    part[tid] = s;
    __syncthreads();
    for (int off = 1; off < SCAN_THREADS; off <<= 1) {
        unsigned tv = (tid >= off) ? part[tid - off] : 0u;
        __syncthreads();
        part[tid] += tv;
        __syncthreads();
    }
    unsigned pre = (tid > 0) ? part[tid - 1] : 0u;
    #pragma unroll
    for (int k = 0; k < BINS_PER_THREAD; ++k)
        if (base + k < NBUCKETS) offs[base + k] = pre + loc[k];
}

// ---- K3: scatter points into bucket order (x,y,z,id as float4) ----------
__global__ __launch_bounds__(256) void k3_scatter(
    const vfloat4* __restrict__ X4, unsigned* __restrict__ offs,
    vfloat4* __restrict__ sorted, float scale)
{
    int t = blockIdx.x * blockDim.x + threadIdx.x;
    vfloat4 q0 = __builtin_nontemporal_load(&X4[3 * t + 0]);
    vfloat4 q1 = __builtin_nontemporal_load(&X4[3 * t + 1]);
    vfloat4 q2 = __builtin_nontemporal_load(&X4[3 * t + 2]);

    float px[4] = {q0.x, q0.w, q1.z, q2.y};
    float py[4] = {q0.y, q1.x, q1.w, q2.z};
    float pz[4] = {q0.z, q1.y, q2.x, q2.w};

    #pragma unroll
    for (int p = 0; p < 4; ++p) {
        unsigned b = bucket_of(px[p], py[p], pz[p], scale);
        unsigned pos = atomicAdd(&offs[b], 1u);
        vfloat4 rec = {px[p], py[p], pz[p],
                       __uint_as_float((unsigned)(4 * t + p))};
        __builtin_nontemporal_store(rec, &sorted[pos]);
    }
}

// ---- K4: interpolate in sorted order, scatter result to out[id] ---------
__global__ __launch_bounds__(256) void k4_interp(
    const vfloat4* __restrict__ sorted, const float2* __restrict__ tb,
    vfloat2* __restrict__ out, float scale)
{
    int i = blockIdx.x * blockDim.x + threadIdx.x;
    vfloat4 s = __builtin_nontemporal_load(&sorted[i]);

    float xs = s.x * scale;
    float ys = s.y * scale;
    float zs = s.z * scale;

    float fx = floorf(xs), fy = floorf(ys), fz = floorf(zs);
    float wx = xs - fx, wy = ys - fy, wz = zs - fz;

    unsigned hx0 = (unsigned)(int)fx;
    unsigned hy0 = (unsigned)(int)fy * PRIME_Y;
    unsigned hz0 = (unsigned)(int)fz * PRIME_Z;
    unsigned hx1 = (unsigned)(int)ceilf(xs);
    unsigned hy1 = (unsigned)(int)ceilf(ys) * PRIME_Y;
    unsigned hz1 = (unsigned)(int)ceilf(zs) * PRIME_Z;

    // corner c = (bx<<2)|(by<<1)|bz ; table loads stay normally cached.
    float2 v0 = tb[(hx0 ^ hy0 ^ hz0) & HT_MASK];
    float2 v1 = tb[(hx0 ^ hy0 ^ hz1) & HT_MASK];
    float2 v2 = tb[(hx0 ^ hy1 ^ hz0) & HT_MASK];
    float2 v3 = tb[(hx0 ^ hy1 ^ hz1) & HT_MASK];
    float2 v4 = tb[(hx1 ^ hy0 ^ hz0) & HT_MASK];
    float2 v5 = tb[(hx1 ^ hy0 ^ hz1) & HT_MASK];
    float2 v6 = tb[(hx1 ^ hy1 ^ hz0) & HT_MASK];
    float2 v7 = tb[(hx1 ^ hy1 ^ hz1) & HT_MASK];

    float omx = 1.0f - wx, omy = 1.0f - wy, omz = 1.0f - wz;

    float p00x = v0.x * omx + v4.x * wx;
    float p00y = v0.y * omx + v4.y * wx;
    float p01x = v1.x * omx + v5.x * wx;
    float p01y = v1.y * omx + v5.y * wx;
    float p10x = v2.x * omx + v6.x * wx;
    float p10y = v2.y * omx + v6.y * wx;
    float p11x = v3.x * omx + v7.x * wx;
    float p11y = v3.y * omx + v7.y * wx;

    float p0x = p00x * omy + p10x * wy;
    float p0y = p00y * omy + p10y * wy;
    float p1x = p01x * omy + p11x * wy;
    float p1y = p01y * omy + p11y * wy;

    vfloat2 r = {p0x * omz + p1x * wz, p0y * omz + p1y * wz};
    unsigned id = __float_as_uint(s.w);
    __builtin_nontemporal_store(r, &out[id]);
}

// ---- Fallback: known-good direct kernel (r1, 62us) -----------------------
__global__ __launch_bounds__(256) void direct_interp(
    const float* __restrict__ X, const float2* __restrict__ tb,
    float2* __restrict__ out, float scale)
{
    int i = blockIdx.x * blockDim.x + threadIdx.x;
    float xs = X[3 * i + 0] * scale;
    float ys = X[3 * i + 1] * scale;
    float zs = X[3 * i + 2] * scale;

    float fx = floorf(xs), fy = floorf(ys), fz = floorf(zs);
    float wx = xs - fx, wy = ys - fy, wz = zs - fz;

    unsigned hx0 = (unsigned)(int)fx;
    unsigned hy0 = (unsigned)(int)fy * PRIME_Y;
    unsigned hz0 = (unsigned)(int)fz * PRIME_Z;
    unsigned hx1 = (unsigned)(int)ceilf(xs);
    unsigned hy1 = (unsigned)(int)ceilf(ys) * PRIME_Y;
    unsigned hz1 = (unsigned)(int)ceilf(zs) * PRIME_Z;

    float2 v0 = tb[(hx0 ^ hy0 ^ hz0) & HT_MASK];
    float2 v1 = tb[(hx0 ^ hy0 ^ hz1) & HT_MASK];
    float2 v2 = tb[(hx0 ^ hy1 ^ hz0) & HT_MASK];
    float2 v3 = tb[(hx0 ^ hy1 ^ hz1) & HT_MASK];
    float2 v4 = tb[(hx1 ^ hy0 ^ hz0) & HT_MASK];
    float2 v5 = tb[(hx1 ^ hy0 ^ hz1) & HT_MASK];
    float2 v6 = tb[(hx1 ^ hy1 ^ hz0) & HT_MASK];
    float2 v7 = tb[(hx1 ^ hy1 ^ hz1) & HT_MASK];

    float omx = 1.0f - wx, omy = 1.0f - wy, omz = 1.0f - wz;
    float p00x = v0.x * omx + v4.x * wx;
    float p00y = v0.y * omx + v4.y * wx;
    float p01x = v1.x * omx + v5.x * wx;
    float p01y = v1.y * omx + v5.y * wx;
    float p10x = v2.x * omx + v6.x * wx;
    float p10y = v2.y * omx + v6.y * wx;
    float p11x = v3.x * omx + v7.x * wx;
    float p11y = v3.y * omx + v7.y * wx;
    float p0x = p00x * omy + p10x * wy;
    float p0y = p00y * omy + p10y * wy;
    float p1x = p01x * omy + p11x * wy;
    float p1y = p01y * omy + p11y * wy;

    float2 r;
    r.x = p0x * omz + p1x * wz;
    r.y = p0y * omz + p1y * wz;
    out[i] = r;
}

extern "C" void kernel_launch(void* const* d_in, const int* in_sizes, int n_in,
                              void* d_out, int out_size, void* d_ws, size_t ws_size,
                              hipStream_t stream) {
    const float* X      = (const float*)d_in[0];
    const vfloat4* X4   = (const vfloat4*)d_in[0];
    const float2* table = (const float2*)d_in[1];

    // RES computed exactly as the reference does (double precision on host).
    double growth = exp((log(512.0) - log(16.0)) / 15.0);
    double res = pow(growth, 8.0) * 16.0;
    float scale = (float)(res - 1.0);

    const size_t histBytes = (size_t)NBUCKETS * sizeof(unsigned);
    const size_t needed = 2 * histBytes + (size_t)N_POINTS * 16;

    if (ws_size < needed) {
        // Not enough scratch: known-good direct kernel.
        direct_interp<<<N_POINTS / 256, 256, 0, stream>>>(
            X, table, (float2*)d_out, scale);
        return;
    }

    unsigned* hist  = (unsigned*)d_ws;
    unsigned* offs  = hist + NBUCKETS;
    vfloat4* sorted = (vfloat4*)((char*)d_ws + 2 * histBytes); // 16B aligned

    hipMemsetAsync(hist, 0, histBytes, stream);
    k1_hist<<<N_POINTS / (256 * 4), 256, 0, stream>>>(X4, hist, scale);
    k2_scan<<<1, SCAN_THREADS, 0, stream>>>(hist, offs);
    k3_scatter<<<N_POINTS / (256 * 4), 256, 0, stream>>>(X4, offs, sorted, scale);
    k4_interp<<<N_POINTS / 256, 256, 0, stream>>>(sorted, table,
                                                  (vfloat2*)d_out, scale);
}

// Round 9
// 61.746 us; speedup vs baseline: 5.7958x; 5.7958x over previous
//
#include <hip/hip_runtime.h>
#include <math.h>

// Hash-grid (instant-NGP style) trilinear interpolation, layer 8.
// T = 2^19 entries x F=2 floats; N = 2^21 points x 3 dims.
// Hash: (ix ^ iy*2654435761 ^ iz*805459861) mod 2^19 -- uint32 math is
// bit-exact with the reference's int64 (power-of-two modulus).
//
// FINAL evidence ledger (why this simple kernel is the keeper):
//  r1 direct (this kernel):            61.9 us  <- best
//  r3 4pts/thread, 32-deep gathers:    64.4 us  (flat: not latency-bound)
//  r6 XOR-1 pair loads, -25% requests: 61.8 us  (flat: not addr-rate-bound;
//     x-pairs were already implicitly line-merged)
//  r7 sc0 L1-bypass (L2 kept):         78 us    (L1 path helps)
//  r5 nt gathers (L2 broken):          146 us   (table must stay L2-cached)
//  r8 spatial counting-sort pipeline:  358 us   (scatter write-amp 137MB;
//     points(32MB) >> table(4MB) -> reordering structurally loses)
// Wall: ~6 unique random 128B table-line fills per point from L2
// (2M x 6 x 128B ~= 1.5GB at ~25TB/s random fill ~= 60us). The hash
// destroys all locality except the x-LSB pair; no further reduction
// available without reordering, which costs more than it saves.

#define HT_MASK  524287u
#define PRIME_Y  2654435761u
#define PRIME_Z  805459861u
#define N_POINTS 2097152

__global__ __launch_bounds__(256) void hashgrid_interp_kernel(
    const float* __restrict__ X,
    const float* __restrict__ table,   // T x 2 floats
    float2* __restrict__ out,
    float scale)                        // (float)(RES - 1.0)
{
    int i = blockIdx.x * blockDim.x + threadIdx.x;
    if (i >= N_POINTS) return;

    float xs = X[3 * i + 0] * scale;
    float ys = X[3 * i + 1] * scale;
    float zs = X[3 * i + 2] * scale;

    float fx = floorf(xs), fy = floorf(ys), fz = floorf(zs);
    float wx = xs - fx,   wy = ys - fy,   wz = zs - fz;

    unsigned hx0 = (unsigned)(int)fx;
    unsigned hy0 = (unsigned)(int)fy * PRIME_Y;
    unsigned hz0 = (unsigned)(int)fz * PRIME_Z;
    unsigned hx1 = (unsigned)(int)ceilf(xs);
    unsigned hy1 = (unsigned)(int)ceilf(ys) * PRIME_Y;
    unsigned hz1 = (unsigned)(int)ceilf(zs) * PRIME_Z;

    const float2* tb = (const float2*)table;

    // corner c = (bx<<2) | (by<<1) | bz  (bit2 -> x uses ceil, etc.)
    float2 v0 = tb[(hx0 ^ hy0 ^ hz0) & HT_MASK];
    float2 v1 = tb[(hx0 ^ hy0 ^ hz1) & HT_MASK];
    float2 v2 = tb[(hx0 ^ hy1 ^ hz0) & HT_MASK];
    float2 v3 = tb[(hx0 ^ hy1 ^ hz1) & HT_MASK];
    float2 v4 = tb[(hx1 ^ hy0 ^ hz0) & HT_MASK];
    float2 v5 = tb[(hx1 ^ hy0 ^ hz1) & HT_MASK];
    float2 v6 = tb[(hx1 ^ hy1 ^ hz0) & HT_MASK];
    float2 v7 = tb[(hx1 ^ hy1 ^ hz1) & HT_MASK];

    float omx = 1.0f - wx, omy = 1.0f - wy, omz = 1.0f - wz;

    float p00x = v0.x * omx + v4.x * wx;
    float p00y = v0.y * omx + v4.y * wx;
    float p01x = v1.x * omx + v5.x * wx;
    float p01y = v1.y * omx + v5.y * wx;
    float p10x = v2.x * omx + v6.x * wx;
    float p10y = v2.y * omx + v6.y * wx;
    float p11x = v3.x * omx + v7.x * wx;
    float p11y = v3.y * omx + v7.y * wx;

    float p0x = p00x * omy + p10x * wy;
    float p0y = p00y * omy + p10y * wy;
    float p1x = p01x * omy + p11x * wy;
    float p1y = p01y * omy + p11y * wy;

    float2 r;
    r.x = p0x * omz + p1x * wz;
    r.y = p0y * omz + p1y * wz;
    out[i] = r;
}

extern "C" void kernel_launch(void* const* d_in, const int* in_sizes, int n_in,
                              void* d_out, int out_size, void* d_ws, size_t ws_size,
                              hipStream_t stream) {
    const float* X     = (const float*)d_in[0];
    const float* table = (const float*)d_in[1];
    float2* out = (float2*)d_out;

    // RES computed exactly as the reference does (double precision on host).
    double growth = exp((log(512.0) - log(16.0)) / 15.0);
    double res = pow(growth, 8.0) * 16.0;
    float scale = (float)(res - 1.0);

    int block = 256;
    int grid = (N_POINTS + block - 1) / block;  // 8192 blocks
    hashgrid_interp_kernel<<<grid, block, 0, stream>>>(X, table, out, scale);
}